// Round 1
// baseline (14189.253 us; speedup 1.0000x reference)
//
#include <hip/hip_runtime.h>

#define EMB   300
#define EMB2  600
#define NLAYERS 5
#define NN    100000
#define NE    400000
#define NG    1024
#define BN_EPS 1e-5f

// ---------------- CSR build ----------------
__global__ void k_count(const int* __restrict__ dst, int* __restrict__ cnt) {
  int e = blockIdx.x * 256 + threadIdx.x;
  if (e < NE) atomicAdd(&cnt[dst[e]], 1);
}

__global__ void k_scan(const int* __restrict__ cnt, int* __restrict__ rowptr,
                       int* __restrict__ cursor) {
  __shared__ int part[1024];
  int t = threadIdx.x;
  const int CH = (NN + 1023) / 1024;  // 98
  int base = t * CH;
  int s = 0;
  for (int i = 0; i < CH; i++) { int idx = base + i; if (idx < NN) s += cnt[idx]; }
  part[t] = s; __syncthreads();
  for (int off = 1; off < 1024; off <<= 1) {
    int v = (t >= off) ? part[t - off] : 0;
    __syncthreads();
    part[t] += v;
    __syncthreads();
  }
  int run = (t == 0) ? 0 : part[t - 1];
  for (int i = 0; i < CH; i++) {
    int idx = base + i;
    if (idx < NN) { rowptr[idx] = run; cursor[idx] = run; run += cnt[idx]; }
  }
  if (t == 1023) rowptr[NN] = part[1023];
}

__global__ void k_fill(const int* __restrict__ ei, const int* __restrict__ ea,
                       int* __restrict__ cursor, int* __restrict__ packed) {
  int e = blockIdx.x * 256 + threadIdx.x;
  if (e >= NE) return;
  int d = ei[NE + e];           // dst
  int s = ei[e];                // src
  int comb = ea[2 * e] * 3 + ea[2 * e + 1];   // both in [0,3)
  int pos = atomicAdd(&cursor[d], 1);
  packed[pos] = s | (comb << 20);   // src < 2^17
}

// ---------------- init h ----------------
__global__ void k_init(const int* __restrict__ x, const float4* __restrict__ ae1,
                       const float4* __restrict__ ae2, float4* __restrict__ h) {
  int idx = blockIdx.x * 256 + threadIdx.x;
  if (idx >= NN * 75) return;
  int n = idx / 75, v = idx - n * 75;
  int x0 = x[2 * n], x1 = x[2 * n + 1];
  float4 a = ae1[x0 * 75 + v], b = ae2[x1 * 75 + v];
  float4 r; r.x = a.x + b.x; r.y = a.y + b.y; r.z = a.z + b.z; r.w = a.w + b.w;
  h[idx] = r;
}

// ---------------- aggregation (wave per node) ----------------
__global__ __launch_bounds__(256) void k_agg(
    const float* __restrict__ h, const int* __restrict__ rowptr,
    const int* __restrict__ packed, const float* __restrict__ be1,
    const float* __restrict__ be2, float* __restrict__ agg) {
  __shared__ float tab[9 * EMB];   // 9 distinct (ea0, ea1) edge embeddings
  for (int i = threadIdx.x; i < 9 * EMB; i += 256) {
    int cc = i / EMB, d = i - cc * EMB;
    tab[i] = be1[(cc / 3) * EMB + d] + be2[(cc - (cc / 3) * 3) * EMB + d];
  }
  __syncthreads();
  int ty = threadIdx.x >> 6, lane = threadIdx.x & 63;
  int n = blockIdx.x * 4 + ty;
  float acc[5];
#pragma unroll
  for (int j = 0; j < 5; j++) {
    int d = lane + 64 * j;
    if (d < EMB) acc[j] = h[(size_t)n * EMB + d] + be1[4 * EMB + d] + be2[d]; // + self_emb
  }
  int e0 = rowptr[n], e1 = rowptr[n + 1];
  for (int e = e0; e < e1; ++e) {
    int pk = packed[e];
    const float* hr = &h[(size_t)(pk & 0xFFFFF) * EMB];
    const float* tr = &tab[(pk >> 20) * EMB];
#pragma unroll
    for (int j = 0; j < 5; j++) {
      int d = lane + 64 * j;
      if (d < EMB) acc[j] += hr[d] + tr[d];
    }
  }
#pragma unroll
  for (int j = 0; j < 5; j++) {
    int d = lane + 64 * j;
    if (d < EMB) agg[(size_t)n * EMB + d] = acc[j];
  }
}

// ---------------- fp32 tiled GEMM: C = (relu?)(A@B + bias) ----------------
// A: MxK row-major, B: KxN row-major
#define BM 64
#define BN 64
#define BKT 16
template <bool RELU>
__global__ __launch_bounds__(256) void k_gemm(
    const float* __restrict__ A, const float* __restrict__ B,
    const float* __restrict__ bias, float* __restrict__ C,
    int M, int K, int N) {
  __shared__ float As[BKT][BM + 4];
  __shared__ float Bs[BKT][BN];
  int t = threadIdx.x;
  int tx = t & 15, ty = t >> 4;
  int row0 = blockIdx.y * BM, col0 = blockIdx.x * BN;
  float acc[4][4] = {};
  int nk = (K + BKT - 1) / BKT;
  for (int kt = 0; kt < nk; ++kt) {
    int k0 = kt * BKT;
#pragma unroll
    for (int i = 0; i < 4; ++i) {   // A tile: 64m x 16k
      int li = t + i * 256;
      int m = li >> 4, kk = li & 15;
      int r = row0 + m, k = k0 + kk;
      As[kk][m] = (r < M && k < K) ? A[(size_t)r * K + k] : 0.f;
    }
#pragma unroll
    for (int i = 0; i < 4; ++i) {   // B tile: 16k x 64n
      int li = t + i * 256;
      int n = li & 63, kk = li >> 6;
      int k = k0 + kk, c = col0 + n;
      Bs[kk][n] = (k < K && c < N) ? B[(size_t)k * N + c] : 0.f;
    }
    __syncthreads();
#pragma unroll
    for (int kk = 0; kk < BKT; ++kk) {
      float4 a4 = *(const float4*)&As[kk][ty * 4];
      float4 b4 = *(const float4*)&Bs[kk][tx * 4];
      float a[4] = {a4.x, a4.y, a4.z, a4.w};
      float b[4] = {b4.x, b4.y, b4.z, b4.w};
#pragma unroll
      for (int i = 0; i < 4; i++)
#pragma unroll
        for (int j = 0; j < 4; j++) acc[i][j] += a[i] * b[j];
    }
    __syncthreads();
  }
#pragma unroll
  for (int i = 0; i < 4; i++) {
    int r = row0 + ty * 4 + i;
    if (r >= M) continue;
#pragma unroll
    for (int j = 0; j < 4; j++) {
      int c = col0 + tx * 4 + j;
      if (c < N) {
        float v = acc[i][j] + bias[c];
        if (RELU) v = fmaxf(v, 0.f);
        C[(size_t)r * N + c] = v;
      }
    }
  }
}

// ---------------- batchnorm ----------------
__global__ void k_bnstats(const float* __restrict__ h, float* __restrict__ stats) {
  int b = blockIdx.x, t = threadIdx.x;
  int r0 = b * 196, r1 = r0 + 196; if (r1 > NN) r1 = NN;
  if (r0 >= NN) return;
  int c2 = t + 256;
  float s1 = 0, ss1 = 0, s2 = 0, ss2 = 0;
  for (int r = r0; r < r1; ++r) {
    float v1 = h[(size_t)r * EMB + t];
    s1 += v1; ss1 += v1 * v1;
    if (c2 < EMB) { float v2 = h[(size_t)r * EMB + c2]; s2 += v2; ss2 += v2 * v2; }
  }
  atomicAdd(&stats[t], s1); atomicAdd(&stats[EMB + t], ss1);
  if (c2 < EMB) { atomicAdd(&stats[c2], s2); atomicAdd(&stats[EMB + c2], ss2); }
}

__global__ void k_bnfinal(const float* __restrict__ stats, const float* __restrict__ sc,
                          const float* __restrict__ bi, float* __restrict__ coef) {
  int c = threadIdx.x;
  if (c >= EMB) return;
  float mean = stats[c] * (1.0f / NN);
  float var  = stats[EMB + c] * (1.0f / NN) - mean * mean;
  float inv  = rsqrtf(var + BN_EPS);
  float a = inv * sc[c];
  coef[c] = a;
  coef[EMB + c] = bi[c] - mean * a;
}

__global__ void k_bnapply(float4* __restrict__ h, const float* __restrict__ coef, int relu) {
  int idx = blockIdx.x * 256 + threadIdx.x;
  if (idx >= NN * 75) return;
  int v = idx % 75;
  float4 a  = *(const float4*)&coef[v * 4];
  float4 bb = *(const float4*)&coef[EMB + v * 4];
  float4 x = h[idx];
  x.x = x.x * a.x + bb.x; x.y = x.y * a.y + bb.y;
  x.z = x.z * a.z + bb.z; x.w = x.w * a.w + bb.w;
  if (relu) { x.x = fmaxf(x.x, 0.f); x.y = fmaxf(x.y, 0.f);
              x.z = fmaxf(x.z, 0.f); x.w = fmaxf(x.w, 0.f); }
  h[idx] = x;
}

// ---------------- pooling (batch is sorted) ----------------
__device__ __forceinline__ int lowerb(const int* a, int n, int v) {
  int lo = 0, hi = n;
  while (lo < hi) { int mid = (lo + hi) >> 1; if (a[mid] < v) lo = mid + 1; else hi = mid; }
  return lo;
}

__global__ void k_pool(const float* __restrict__ h, const int* __restrict__ batch,
                       float* __restrict__ pooled) {
  int g = blockIdx.x;
  __shared__ int se[2];
  if (threadIdx.x == 0) { se[0] = lowerb(batch, NN, g); se[1] = lowerb(batch, NN, g + 1); }
  __syncthreads();
  int start = se[0], end = se[1];
  float cntf = (float)((end - start) > 1 ? (end - start) : 1);
  for (int c = threadIdx.x; c < EMB; c += 256) {
    float s = 0.f;
    for (int r = start; r < end; ++r) s += h[(size_t)r * EMB + c];
    pooled[(size_t)g * EMB + c] = s / cntf;
  }
}

// ---------------- projection head ----------------
template <bool RELU>
__global__ void k_rowgemm(const float* __restrict__ X, const float* __restrict__ W,
                          const float* __restrict__ bias, float* __restrict__ Y) {
  int g = blockIdx.x;
  __shared__ float row[EMB];
  for (int i = threadIdx.x; i < EMB; i += 256) row[i] = X[(size_t)g * EMB + i];
  __syncthreads();
  for (int c = threadIdx.x; c < EMB; c += 256) {
    float acc = bias[c];
    for (int k = 0; k < EMB; k++) acc += row[k] * W[(size_t)k * EMB + c];
    if (RELU) acc = fmaxf(acc, 0.f);
    Y[(size_t)g * EMB + c] = acc;
  }
}

__global__ void k_norm(float* __restrict__ p) {
  int g = blockIdx.x;
  __shared__ float red[256];
  float s = 0.f;
  for (int c = threadIdx.x; c < EMB; c += 256) { float v = p[(size_t)g * EMB + c]; s += v * v; }
  red[threadIdx.x] = s; __syncthreads();
  for (int off = 128; off > 0; off >>= 1) {
    if (threadIdx.x < off) red[threadIdx.x] += red[threadIdx.x + off];
    __syncthreads();
  }
  float inv = 1.0f / fmaxf(sqrtf(red[0]), 1e-12f);
  for (int c = threadIdx.x; c < EMB; c += 256) p[(size_t)g * EMB + c] *= inv;
}

__global__ __launch_bounds__(256) void k_logits(const float* __restrict__ feats,
                                                float* __restrict__ out) {
  __shared__ float SA[16 * EMB];
  __shared__ float SB[16 * EMB];
  int t = threadIdx.y * 16 + threadIdx.x;
  int i0 = blockIdx.y * 16, j0 = blockIdx.x * 16;
  for (int idx = t; idx < 16 * EMB; idx += 256) {
    int r = idx / EMB, c = idx - r * EMB;
    SA[idx] = feats[(size_t)(i0 + r) * EMB + c];
    SB[idx] = feats[(size_t)(512 + j0 + r) * EMB + c];
  }
  __syncthreads();
  float acc = 0.f;
  const float* a = &SA[threadIdx.y * EMB];
  const float* b = &SB[threadIdx.x * EMB];
  for (int k = 0; k < EMB; k++) acc += a[k] * b[k];
  out[(size_t)(i0 + threadIdx.y) * 512 + j0 + threadIdx.x] = acc / 0.04f;
}

// ---------------- host ----------------
extern "C" void kernel_launch(void* const* d_in, const int* in_sizes, int n_in,
                              void* d_out, int out_size, void* d_ws, size_t ws_size,
                              hipStream_t stream) {
  const int*   x         = (const int*)d_in[0];
  const int*   ei        = (const int*)d_in[1];
  const int*   ea        = (const int*)d_in[2];
  const int*   batch     = (const int*)d_in[3];
  const float* atom_emb1 = (const float*)d_in[4];
  const float* atom_emb2 = (const float*)d_in[5];
  const float* bond_emb1 = (const float*)d_in[6];
  const float* bond_emb2 = (const float*)d_in[7];
  const float* W1        = (const float*)d_in[8];
  const float* b1        = (const float*)d_in[9];
  const float* W2        = (const float*)d_in[10];
  const float* b2        = (const float*)d_in[11];
  const float* bn_scale  = (const float*)d_in[12];
  const float* bn_bias   = (const float*)d_in[13];
  const float* pW1       = (const float*)d_in[14];
  const float* pb1       = (const float*)d_in[15];
  const float* pW2       = (const float*)d_in[16];
  const float* pb2       = (const float*)d_in[17];
  float* out = (float*)d_out;

  char* w = (char*)d_ws;
  size_t used = 0;
  auto alloc = [&](size_t bytes) {
    char* p = w + used;
    used += (bytes + 255) & ~(size_t)255;
    return p;
  };
  float* h      = (float*)alloc((size_t)NN * EMB * 4);
  float* agg    = (float*)alloc((size_t)NN * EMB * 4);
  int*   cnt    = (int*)alloc(NN * 4);
  int*   rowptr = (int*)alloc((NN + 4) * 4);
  int*   cursor = (int*)alloc(NN * 4);
  int*   packed = (int*)alloc(NE * 4);
  float* stats  = (float*)alloc(EMB2 * 4);
  float* coef   = (float*)alloc(EMB2 * 4);
  float* pooled = (float*)alloc((size_t)NG * EMB * 4);
  float* t1     = (float*)alloc((size_t)NG * EMB * 4);
  float* feats  = (float*)alloc((size_t)NG * EMB * 4);
  // h1 chunk buffer gets whatever remains (cap at 25000 rows)
  long long avail = (long long)ws_size - (long long)used;
  long long rows = avail / ((long long)EMB2 * 4);
  int CHUNK = (int)(rows < 25000 ? rows : 25000);
  if (CHUNK < 64) CHUNK = 64;
  float* h1 = (float*)(w + used);

  // CSR build (once; shared by all 5 layers)
  hipMemsetAsync(cnt, 0, NN * 4, stream);
  k_count<<<(NE + 255) / 256, 256, 0, stream>>>(ei + NE, cnt);
  k_scan<<<1, 1024, 0, stream>>>(cnt, rowptr, cursor);
  k_fill<<<(NE + 255) / 256, 256, 0, stream>>>(ei, ea, cursor, packed);

  // h0 = atom_emb1[x0] + atom_emb2[x1]
  k_init<<<(NN * 75 + 255) / 256, 256, 0, stream>>>(
      x, (const float4*)atom_emb1, (const float4*)atom_emb2, (float4*)h);

  for (int l = 0; l < NLAYERS; ++l) {
    const float* be1 = bond_emb1 + (size_t)l * 6 * EMB;
    const float* be2 = bond_emb2 + (size_t)l * 3 * EMB;
    k_agg<<<NN / 4, 256, 0, stream>>>(h, rowptr, packed, be1, be2, agg);

    for (int c0 = 0; c0 < NN; c0 += CHUNK) {
      int m = NN - c0 < CHUNK ? NN - c0 : CHUNK;
      dim3 g1((EMB2 + BN - 1) / BN, (m + BM - 1) / BM);
      k_gemm<true><<<g1, 256, 0, stream>>>(
          agg + (size_t)c0 * EMB, W1 + (size_t)l * EMB * EMB2, b1 + (size_t)l * EMB2,
          h1, m, EMB, EMB2);
      dim3 g2((EMB + BN - 1) / BN, (m + BM - 1) / BM);
      k_gemm<false><<<g2, 256, 0, stream>>>(
          h1, W2 + (size_t)l * EMB2 * EMB, b2 + (size_t)l * EMB,
          h + (size_t)c0 * EMB, m, EMB2, EMB);
    }

    hipMemsetAsync(stats, 0, EMB2 * 4, stream);
    k_bnstats<<<512, 256, 0, stream>>>(h, stats);
    k_bnfinal<<<1, 320, 0, stream>>>(stats, bn_scale + (size_t)l * EMB,
                                     bn_bias + (size_t)l * EMB, coef);
    k_bnapply<<<(NN * 75 + 255) / 256, 256, 0, stream>>>((float4*)h, coef, l < NLAYERS - 1);
  }

  k_pool<<<NG, 256, 0, stream>>>(h, batch, pooled);
  k_rowgemm<true><<<NG, 256, 0, stream>>>(pooled, pW1, pb1, t1);
  k_rowgemm<false><<<NG, 256, 0, stream>>>(t1, pW2, pb2, feats);
  k_norm<<<NG, 256, 0, stream>>>(feats);
  k_logits<<<dim3(32, 32), dim3(16, 16), 0, stream>>>(feats, out);
}